// Round 2
// baseline (219.623 us; speedup 1.0000x reference)
//
#include <hip/hip_runtime.h>
#include <hip/hip_bf16.h>
#include <cstdint>

#define BATCH 16
#define TTOT  4096
#define DIN   512
#define DOUT  512
#define NG    8

typedef float f32x4 __attribute__((ext_vector_type(4)));
typedef short s16x8 __attribute__((ext_vector_type(8)));

__device__ __forceinline__ short f2b(float f) {
    union { __bf16 b; short s; } u; u.b = (__bf16)f; return u.s;
}

// ---- Kernel 1: convert W (8x512x512 fp32) to bf16 in workspace ----
__global__ void wconv_kernel(const float* __restrict__ W, ushort* __restrict__ wbf) {
    int i = blockIdx.x * blockDim.x + threadIdx.x;   // each thread: 4 elems
    float4 v = reinterpret_cast<const float4*>(W)[i];
    ushort4 o;
    o.x = (ushort)f2b(v.x); o.y = (ushort)f2b(v.y);
    o.z = (ushort)f2b(v.z); o.w = (ushort)f2b(v.w);
    reinterpret_cast<ushort4*>(wbf)[i] = o;
}

// ---- Kernel 2: grouped GEMM, BM=64 BN=128 BK=64, 4 waves (2x2), dbuf LDS ----
// Grid: 1-D 4096 blocks, XCD-chunked: p -> (xcd=p&7, j=p>>3), logical l =
// xcd*512 + j, mt = l>>2 (token tile), nt = l&3 (col tile, fastest within XCD)
template<bool WSB>
__launch_bounds__(256)
__global__ void gemm_kernel(const float* __restrict__ x,
                            const float* __restrict__ W,
                            const ushort* __restrict__ wbf,
                            const float* __restrict__ bias,
                            float* __restrict__ out) {
    // LDS plan: A dbuf @ [0, 16KB), B dbuf @ [16KB, 48KB); epilogue C-tile
    // (64x132 f32 = 33KB) overlays the same memory after the K loop.
    __shared__ __align__(16) char smem[49152];

    const int tid  = threadIdx.x;
    const int lane = tid & 63;
    const int wid  = tid >> 6;
    const int wm   = wid >> 1;      // 0..1 : 32-row slab
    const int wn   = wid & 1;       // 0..1 : 64-col slab

    const int p  = blockIdx.x;
    const int l  = ((p & 7) << 9) + (p >> 3);   // XCD-chunked logical id
    const int mt = l >> 2;
    const int nt = l & 3;
    const int bb = mt >> 6;                 // batch
    const int t0 = (mt & 63) << 6;          // token tile start (mult of 64)
    const int n0 = nt << 7;                 // output-col tile start

    // group lookup (boundaries are compile-time consts)
    int g = 0;
    if (t0 >= 256)  g++;
    if (t0 >= 768)  g++;
    if (t0 >= 1536) g++;
    if (t0 >= 1920) g++;
    if (t0 >= 2560) g++;
    if (t0 >= 3072) g++;
    if (t0 >= 3648) g++;

    // A staging: thread covers row=tid/4, 16 consecutive fp32 at col (tid%4)*16
    const int arow = tid >> 2;
    const int acol = (tid & 3) << 4;
    const float* aptr = x + ((size_t)(bb * TTOT + t0 + arow)) * DIN + acol;

    // staging registers
    float4 a0, a1, a2, a3;
    int4   bvi[4];
    float4 bw0[4], bw1[4];

    auto load_global = [&](int k0) {
        a0 = *reinterpret_cast<const float4*>(aptr + k0);
        a1 = *reinterpret_cast<const float4*>(aptr + k0 + 4);
        a2 = *reinterpret_cast<const float4*>(aptr + k0 + 8);
        a3 = *reinterpret_cast<const float4*>(aptr + k0 + 12);
#pragma unroll
        for (int pp = 0; pp < 4; ++pp) {
            int idx = pp * 256 + tid;
            int row = idx >> 3, seg = idx & 7;
            if (WSB) {
                bvi[pp] = *reinterpret_cast<const int4*>(
                    wbf + ((size_t)((g << 9) + n0 + row)) * DIN + k0 + (seg << 3));
            } else {
                const float* wp = W + ((size_t)((g << 9) + n0 + row)) * DIN + k0 + (seg << 3);
                bw0[pp] = *reinterpret_cast<const float4*>(wp);
                bw1[pp] = *reinterpret_cast<const float4*>(wp + 4);
            }
        }
    };

    auto swz = [](int row, int bc) { return (row << 7) + (bc ^ ((row & 7) << 4)); };

    auto write_lds = [&](int buf) {
        char* ab  = smem + buf * 8192;            // A: 64x64 bf16 = 8KB
        char* bb_ = smem + 16384 + buf * 16384;   // B: 128x64 bf16 = 16KB
        s16x8 w0, w1;
        w0[0] = f2b(a0.x); w0[1] = f2b(a0.y); w0[2] = f2b(a0.z); w0[3] = f2b(a0.w);
        w0[4] = f2b(a1.x); w0[5] = f2b(a1.y); w0[6] = f2b(a1.z); w0[7] = f2b(a1.w);
        w1[0] = f2b(a2.x); w1[1] = f2b(a2.y); w1[2] = f2b(a2.z); w1[3] = f2b(a2.w);
        w1[4] = f2b(a3.x); w1[5] = f2b(a3.y); w1[6] = f2b(a3.z); w1[7] = f2b(a3.w);
        const int abase = acol << 1;   // byte col in bf16 tile
        *(s16x8*)(ab + swz(arow, abase))      = w0;
        *(s16x8*)(ab + swz(arow, abase + 16)) = w1;
#pragma unroll
        for (int pp = 0; pp < 4; ++pp) {
            int idx = pp * 256 + tid;
            int row = idx >> 3, seg = idx & 7;
            if (WSB) {
                *(int4*)(bb_ + swz(row, seg << 4)) = bvi[pp];
            } else {
                s16x8 wv;
                wv[0] = f2b(bw0[pp].x); wv[1] = f2b(bw0[pp].y);
                wv[2] = f2b(bw0[pp].z); wv[3] = f2b(bw0[pp].w);
                wv[4] = f2b(bw1[pp].x); wv[5] = f2b(bw1[pp].y);
                wv[6] = f2b(bw1[pp].z); wv[7] = f2b(bw1[pp].w);
                *(s16x8*)(bb_ + swz(row, seg << 4)) = wv;
            }
        }
    };

    f32x4 acc[2][4];
#pragma unroll
    for (int mi = 0; mi < 2; ++mi)
#pragma unroll
        for (int ni = 0; ni < 4; ++ni)
            acc[mi][ni] = (f32x4){0.f, 0.f, 0.f, 0.f};

    const int colf = lane & 15;
    const int kgrp = lane >> 4;

    auto compute = [&](int buf) {
        const char* ab  = smem + buf * 8192;
        const char* bb_ = smem + 16384 + buf * 16384;
#pragma unroll
        for (int ks = 0; ks < 2; ++ks) {
            const int kb = ks * 64 + kgrp * 16;   // byte col of this lane's K-octet
            s16x8 af[2], bf[4];
#pragma unroll
            for (int mi = 0; mi < 2; ++mi)
                af[mi] = *(const s16x8*)(ab + swz(wm * 32 + mi * 16 + colf, kb));
#pragma unroll
            for (int ni = 0; ni < 4; ++ni)
                bf[ni] = *(const s16x8*)(bb_ + swz(wn * 64 + ni * 16 + colf, kb));
#pragma unroll
            for (int mi = 0; mi < 2; ++mi)
#pragma unroll
                for (int ni = 0; ni < 4; ++ni)
                    acc[mi][ni] = __builtin_amdgcn_mfma_f32_16x16x32_bf16(
                        af[mi], bf[ni], acc[mi][ni], 0, 0, 0);
        }
    };

    // prologue
    load_global(0);
    write_lds(0);
    __syncthreads();

    int buf = 0;
#pragma unroll 1
    for (int kt = 0; kt < 8; ++kt) {
        if (kt < 7) load_global((kt + 1) << 6);   // issue next tile's loads early
        compute(buf);
        if (kt < 7) write_lds(buf ^ 1);
        __syncthreads();
        buf ^= 1;
    }
    // final __syncthreads above guarantees all waves are done reading LDS

    // ---- epilogue: stage C tile in LDS (64 x 132 f32), read back coalesced ----
    float* cbuf = (float*)smem;
    const int rowg = lane >> 4;
#pragma unroll
    for (int ni = 0; ni < 4; ++ni) {
        const int c = wn * 64 + ni * 16 + colf;
#pragma unroll
        for (int mi = 0; mi < 2; ++mi) {
            const int r = wm * 32 + mi * 16 + rowg * 4;
            f32x4 v = acc[mi][ni];
            cbuf[(r + 0) * 132 + c] = v[0];
            cbuf[(r + 1) * 132 + c] = v[1];
            cbuf[(r + 2) * 132 + c] = v[2];
            cbuf[(r + 3) * 132 + c] = v[3];
        }
    }
    __syncthreads();

    const int rr = tid >> 5;            // 0..7
    const int cc = (tid & 31) << 2;     // 0..124 (f32 col, x4)
    const float4 bv = *reinterpret_cast<const float4*>(bias + (g << 9) + n0 + cc);
#pragma unroll
    for (int it = 0; it < 8; ++it) {
        const int row = it * 8 + rr;
        float4 v = *reinterpret_cast<const float4*>(cbuf + row * 132 + cc);
        float4 o4;
        o4.x = v.x + bv.x; o4.y = v.y + bv.y;
        o4.z = v.z + bv.z; o4.w = v.w + bv.w;
        *reinterpret_cast<float4*>(
            out + ((size_t)(bb * TTOT) + t0 + row) * DOUT + n0 + cc) = o4;
    }
}

extern "C" void kernel_launch(void* const* d_in, const int* in_sizes, int n_in,
                              void* d_out, int out_size, void* d_ws, size_t ws_size,
                              hipStream_t stream) {
    const float* x    = (const float*)d_in[0];
    const float* W    = (const float*)d_in[1];
    const float* bias = (const float*)d_in[2];
    float* out = (float*)d_out;

    const size_t wbytes = (size_t)NG * DOUT * DIN * sizeof(ushort);  // 4 MB
    ushort* wbf = (ushort*)d_ws;

    const int nblk = BATCH * (TTOT / 64) * (DOUT / 128);  // 4096

    if (ws_size >= wbytes) {
        wconv_kernel<<<(NG * DOUT * DIN / 4 + 255) / 256, 256, 0, stream>>>(W, wbf);
        gemm_kernel<true><<<nblk, 256, 0, stream>>>(x, W, wbf, bias, out);
    } else {
        gemm_kernel<false><<<nblk, 256, 0, stream>>>(x, W, wbf, bias, out);
    }
}

// Round 3
// 97.009 us; speedup vs baseline: 2.2639x; 2.2639x over previous
//
#include <hip/hip_runtime.h>
#include <hip/hip_bf16.h>
#include <cstdint>

#define BATCH 16
#define TTOT  4096
#define DIN   512
#define DOUT  512
#define NG    8
#define NJOB  33
#define NKT   8        // K tiles of 64

typedef float f32x4 __attribute__((ext_vector_type(4)));
typedef short s16x4 __attribute__((ext_vector_type(4)));
typedef short s16x8 __attribute__((ext_vector_type(8)));

__device__ __forceinline__ short f2b(float f) {
    union { __bf16 b; short s; } u; u.b = (__bf16)f; return u.s;
}

// M-tile job table per batch: 31 full 128-row tiles + two 64-row stubs at the
// 3648 group boundary (only boundary not a multiple of 128).
__device__ __constant__ short JT0[NJOB] = {
    0,128, 256,384,512,640, 768,896,1024,1152,1280,1408, 1536,1664,1792,
    1920,2048,2176,2304,2432, 2560,2688,2816,2944, 3072,3200,3328,3456,
    3584, 3648, 3712,3840,3968};
__device__ __constant__ char JG[NJOB] = {
    0,0, 1,1,1,1, 2,2,2,2,2,2, 3,3,3, 4,4,4,4,4, 5,5,5,5, 6,6,6,6, 6, 7, 7,7,7};
__device__ __constant__ char JBM[NJOB] = {
    127,127, 127,127,127,127, 127,127,127,127,127,127, 127,127,127,
    127,127,127,127,127, 127,127,127,127, 127,127,127,127, 63, 63, 127,127,127};
// (stored as bm-1 to fit char; compare row <= bm-1)

// ---- Kernel 1: W fp32 -> bf16, PRE-SWIZZLED LDS-image chunks in workspace ----
// chunk c = (g*4 + nt)*8 + kt, 16384 B each; chunk[row*128 + bc] holds
// bf16 of W[g][nt*128+row][kt*64 + ((bc ^ ((row&7)<<4))>>1)]
__global__ void wconv_kernel(const float* __restrict__ W, ushort* __restrict__ wbf) {
    int gid = blockIdx.x * 256 + threadIdx.x;   // 262144 threads x 16B
    int c = gid >> 10;
    int q = (gid & 1023) << 4;
    int row = q >> 7;
    int bc  = q & 127;
    int kbyte = bc ^ ((row & 7) << 4);
    int kt = c & 7, nt = (c >> 3) & 3, g = c >> 5;
    const float* wp = W + ((size_t)(g * DOUT + nt * 128 + row)) * DIN
                        + kt * 64 + (kbyte >> 1);
    float4 v0 = *reinterpret_cast<const float4*>(wp);
    float4 v1 = *reinterpret_cast<const float4*>(wp + 4);
    s16x8 o;
    o[0]=f2b(v0.x); o[1]=f2b(v0.y); o[2]=f2b(v0.z); o[3]=f2b(v0.w);
    o[4]=f2b(v1.x); o[5]=f2b(v1.y); o[6]=f2b(v1.z); o[7]=f2b(v1.w);
    *reinterpret_cast<s16x8*>((char*)wbf + (size_t)c * 16384 + q) = o;
}

// ---- Kernel 2: grouped GEMM 128x128x64, 8 waves, B via global_load_lds ring3,
//      A reg-staged 2-deep, counted-vmcnt pipeline, raw barriers ----
__launch_bounds__(512, 4)
__global__ void gemm_kernel(const float* __restrict__ x,
                            const ushort* __restrict__ wbf,
                            const float* __restrict__ bias,
                            float* __restrict__ out) {
    __shared__ __align__(16) char smem[81920];  // A dbuf 32K | B ring 48K; C overlay

    const int tid  = threadIdx.x;
    const int lane = tid & 63;
    const int wv   = tid >> 6;      // 0..7
    const int wm   = wv >> 2;       // 0..1 : 64-row slab
    const int wn   = wv & 3;        // 0..3 : 32-col slab

    const int p    = blockIdx.x;
    const int l    = (p & 7) * 264 + (p >> 3);     // XCD-chunked
    const int nt   = l & 3;
    const int rest = l >> 2;                        // 0..527
    const int bbat = rest / NJOB;
    const int job  = rest - bbat * NJOB;
    const int t0   = JT0[job];
    const int g    = JG[job];
    const int bmm1 = JBM[job];                      // bm - 1
    const int n0   = nt << 7;

    const float* xbase = x + ((size_t)(bbat * TTOT + t0)) * DIN;
    const char*  bchunk = (const char*)wbf + (size_t)((g * 4 + nt) * 8) * 16384;

    char* abufs = smem;            // 2 x 16384
    char* bring = smem + 32768;    // 3 x 16384

    // A staging geometry: instr r covers rows arow0 + r*4 (4 contiguous rows per
    // wave instr -> 1KB in 8 cache lines, minimal)
    const int arow0 = (wv << 4) + (lane >> 4);
    const int col16 = lane & 15;
    const float* aptr = xbase + (size_t)arow0 * DIN + (col16 << 2);

    float4 aR0[4], aR1[4];

    f32x4 acc[4][2];
#pragma unroll
    for (int mi = 0; mi < 4; ++mi)
#pragma unroll
        for (int ni = 0; ni < 2; ++ni)
            acc[mi][ni] = (f32x4){0.f, 0.f, 0.f, 0.f};

#define ISSUE_A(j)                                                          \
    if ((j) < NKT) {                                                        \
        const float* s_ = aptr + ((j) << 6);                                \
        if (((j) & 1) == 0) {                                               \
            aR0[0] = *(const float4*)(s_);                                  \
            aR0[1] = *(const float4*)(s_ + 4 * DIN);                        \
            aR0[2] = *(const float4*)(s_ + 8 * DIN);                        \
            aR0[3] = *(const float4*)(s_ + 12 * DIN);                       \
        } else {                                                            \
            aR1[0] = *(const float4*)(s_);                                  \
            aR1[1] = *(const float4*)(s_ + 4 * DIN);                        \
            aR1[2] = *(const float4*)(s_ + 8 * DIN);                        \
            aR1[3] = *(const float4*)(s_ + 12 * DIN);                       \
        }                                                                   \
    }

#define ISSUE_B(j)                                                          \
    if ((j) < NKT) {                                                        \
        const char* src_ = bchunk + (size_t)(j) * 16384 + tid * 16;         \
        char* dst_ = bring + ((j) % 3) * 16384 + (wv << 10);                \
        __builtin_amdgcn_global_load_lds(                                   \
            (const __attribute__((address_space(1))) void*)src_,            \
            (__attribute__((address_space(3))) void*)dst_, 16, 0, 0);       \
        __builtin_amdgcn_global_load_lds(                                   \
            (const __attribute__((address_space(1))) void*)(src_ + 8192),   \
            (__attribute__((address_space(3))) void*)(dst_ + 8192), 16, 0, 0);\
    }

#define CVT_WRITE_A(j)                                                      \
    if ((j) < NKT) {                                                        \
        char* ab_ = abufs + ((j) & 1) * 16384;                              \
        _Pragma("unroll")                                                   \
        for (int r_ = 0; r_ < 4; ++r_) {                                    \
            float4 v_ = (((j) & 1) == 0) ? aR0[r_] : aR1[r_];               \
            s16x4 o_;                                                       \
            o_[0]=f2b(v_.x); o_[1]=f2b(v_.y); o_[2]=f2b(v_.z); o_[3]=f2b(v_.w);\
            int row_ = arow0 + r_ * 4;                                      \
            *(s16x4*)(ab_ + (row_ << 7) + (((col16 << 3)) ^ ((row_ & 7) << 4))) = o_; \
        }                                                                   \
    }

    const int colf = lane & 15;
    const int kg   = lane >> 4;

#define COMPUTE(j)                                                          \
    {                                                                       \
        const char* ab_ = abufs + ((j) & 1) * 16384;                        \
        const char* bb_ = bring + ((j) % 3) * 16384;                        \
        _Pragma("unroll")                                                   \
        for (int ks = 0; ks < 2; ++ks) {                                    \
            const int kb = ks * 64 + kg * 16;                               \
            s16x8 af[4], bf[2];                                             \
            _Pragma("unroll")                                               \
            for (int mi = 0; mi < 4; ++mi) {                                \
                int r_ = wm * 64 + mi * 16 + colf;                          \
                af[mi] = *(const s16x8*)(ab_ + (r_ << 7) + (kb ^ ((r_ & 7) << 4))); \
            }                                                               \
            _Pragma("unroll")                                               \
            for (int ni = 0; ni < 2; ++ni) {                                \
                int r_ = wn * 32 + ni * 16 + colf;                          \
                bf[ni] = *(const s16x8*)(bb_ + (r_ << 7) + (kb ^ ((r_ & 7) << 4))); \
            }                                                               \
            _Pragma("unroll")                                               \
            for (int mi = 0; mi < 4; ++mi)                                  \
                _Pragma("unroll")                                           \
                for (int ni = 0; ni < 2; ++ni)                              \
                    acc[mi][ni] = __builtin_amdgcn_mfma_f32_16x16x32_bf16(  \
                        af[mi], bf[ni], acc[mi][ni], 0, 0, 0);              \
        }                                                                   \
    }

#define FENCE asm volatile("" ::: "memory")
#define WAITV6 asm volatile("s_waitcnt vmcnt(6)" ::: "memory")
#define WAITV0 asm volatile("s_waitcnt vmcnt(0)" ::: "memory")
#define WAITL0 asm volatile("s_waitcnt lgkmcnt(0)" ::: "memory")
#define BARRIER do { FENCE; __builtin_amdgcn_s_barrier(); FENCE; } while (0)

    // ---- prologue: tiles 0 and 1 in flight ----
    ISSUE_A(0); ISSUE_B(0);
    FENCE;
    ISSUE_A(1); ISSUE_B(1);
    FENCE;
    CVT_WRITE_A(0);
    WAITV6;       // B(0) complete (A1+B1 = 6 newer stay in flight)
    WAITL0;
    BARRIER;

#pragma unroll
    for (int kt = 0; kt < NKT; ++kt) {
        ISSUE_A(kt + 2); ISSUE_B(kt + 2);   // 6 VMEM ops (0 at tail)
        FENCE;
        COMPUTE(kt);
        if (kt + 1 < NKT) {
            CVT_WRITE_A(kt + 1);            // compiler waits A(kt+1), keeps rest in flight
            if (kt + 2 < NKT) { WAITV6; }   // B(kt+1) done; A/B(kt+2) ride across
            else              { WAITV0; }   // tail drain
            WAITL0;
            BARRIER;
        }
    }

    WAITL0;
    BARRIER;   // all LDS reads done before C overlay

    // ---- epilogue: stage C (128 x 132 f32) in LDS, write coalesced ----
    float* cbuf = (float*)smem;
#pragma unroll
    for (int mi = 0; mi < 4; ++mi)
#pragma unroll
        for (int ni = 0; ni < 2; ++ni) {
            int r0 = wm * 64 + mi * 16 + kg * 4;
            int c  = wn * 32 + ni * 16 + colf;
            f32x4 v = acc[mi][ni];
            cbuf[(r0 + 0) * 132 + c] = v[0];
            cbuf[(r0 + 1) * 132 + c] = v[1];
            cbuf[(r0 + 2) * 132 + c] = v[2];
            cbuf[(r0 + 3) * 132 + c] = v[3];
        }
    WAITL0;
    BARRIER;

    const int rr = tid >> 5;            // 0..15
    const int cc = (tid & 31) << 2;     // 0..124
    float4 bv = *reinterpret_cast<const float4*>(bias + (g << 9) + n0 + cc);
#pragma unroll
    for (int it = 0; it < 8; ++it) {
        int row = it * 16 + rr;
        if (row <= bmm1) {
            float4 v = *reinterpret_cast<const float4*>(cbuf + row * 132 + cc);
            float4 o4; o4.x = v.x + bv.x; o4.y = v.y + bv.y;
                       o4.z = v.z + bv.z; o4.w = v.w + bv.w;
            *reinterpret_cast<float4*>(
                out + ((size_t)(bbat * TTOT + t0 + row)) * DOUT + n0 + cc) = o4;
        }
    }
#undef ISSUE_A
#undef ISSUE_B
#undef CVT_WRITE_A
#undef COMPUTE
#undef FENCE
#undef WAITV6
#undef WAITV0
#undef WAITL0
#undef BARRIER
}

// ---- Fallback (ws too small): R2's proven 64x128 kernel, fp32 W path ----
__launch_bounds__(256)
__global__ void gemm_fallback(const float* __restrict__ x,
                              const float* __restrict__ W,
                              const float* __restrict__ bias,
                              float* __restrict__ out) {
    __shared__ __align__(16) char smem[49152];
    const int tid  = threadIdx.x;
    const int lane = tid & 63;
    const int wid  = tid >> 6;
    const int wm   = wid >> 1;
    const int wn   = wid & 1;
    const int p  = blockIdx.x;
    const int l  = ((p & 7) << 9) + (p >> 3);
    const int mt = l >> 2;
    const int nt = l & 3;
    const int bb = mt >> 6;
    const int t0 = (mt & 63) << 6;
    const int n0 = nt << 7;
    int g = 0;
    if (t0 >= 256)  g++; if (t0 >= 768)  g++; if (t0 >= 1536) g++;
    if (t0 >= 1920) g++; if (t0 >= 2560) g++; if (t0 >= 3072) g++;
    if (t0 >= 3648) g++;
    const int arow = tid >> 2;
    const int acol = (tid & 3) << 4;
    const float* aptr = x + ((size_t)(bb * TTOT + t0 + arow)) * DIN + acol;
    float4 a0, a1, a2, a3;
    float4 bw0[4], bw1[4];
    auto load_global = [&](int k0) {
        a0 = *(const float4*)(aptr + k0);
        a1 = *(const float4*)(aptr + k0 + 4);
        a2 = *(const float4*)(aptr + k0 + 8);
        a3 = *(const float4*)(aptr + k0 + 12);
#pragma unroll
        for (int pp = 0; pp < 4; ++pp) {
            int idx = pp * 256 + tid;
            int row = idx >> 3, seg = idx & 7;
            const float* wp = W + ((size_t)((g << 9) + n0 + row)) * DIN + k0 + (seg << 3);
            bw0[pp] = *(const float4*)(wp);
            bw1[pp] = *(const float4*)(wp + 4);
        }
    };
    auto swz = [](int row, int bc) { return (row << 7) + (bc ^ ((row & 7) << 4)); };
    auto write_lds = [&](int buf) {
        char* ab  = smem + buf * 8192;
        char* bb_ = smem + 16384 + buf * 16384;
        s16x8 w0, w1;
        w0[0]=f2b(a0.x); w0[1]=f2b(a0.y); w0[2]=f2b(a0.z); w0[3]=f2b(a0.w);
        w0[4]=f2b(a1.x); w0[5]=f2b(a1.y); w0[6]=f2b(a1.z); w0[7]=f2b(a1.w);
        w1[0]=f2b(a2.x); w1[1]=f2b(a2.y); w1[2]=f2b(a2.z); w1[3]=f2b(a2.w);
        w1[4]=f2b(a3.x); w1[5]=f2b(a3.y); w1[6]=f2b(a3.z); w1[7]=f2b(a3.w);
        const int abase = acol << 1;
        *(s16x8*)(ab + swz(arow, abase))      = w0;
        *(s16x8*)(ab + swz(arow, abase + 16)) = w1;
#pragma unroll
        for (int pp = 0; pp < 4; ++pp) {
            int idx = pp * 256 + tid;
            int row = idx >> 3, seg = idx & 7;
            s16x8 wv;
            wv[0]=f2b(bw0[pp].x); wv[1]=f2b(bw0[pp].y);
            wv[2]=f2b(bw0[pp].z); wv[3]=f2b(bw0[pp].w);
            wv[4]=f2b(bw1[pp].x); wv[5]=f2b(bw1[pp].y);
            wv[6]=f2b(bw1[pp].z); wv[7]=f2b(bw1[pp].w);
            *(s16x8*)(bb_ + swz(row, seg << 4)) = wv;
        }
    };
    f32x4 acc[2][4];
#pragma unroll
    for (int mi = 0; mi < 2; ++mi)
#pragma unroll
        for (int ni = 0; ni < 4; ++ni) acc[mi][ni] = (f32x4){0.f,0.f,0.f,0.f};
    const int colf = lane & 15;
    const int kgrp = lane >> 4;
    auto compute = [&](int buf) {
        const char* ab  = smem + buf * 8192;
        const char* bb_ = smem + 16384 + buf * 16384;
#pragma unroll
        for (int ks = 0; ks < 2; ++ks) {
            const int kb = ks * 64 + kgrp * 16;
            s16x8 af[2], bf[4];
#pragma unroll
            for (int mi = 0; mi < 2; ++mi)
                af[mi] = *(const s16x8*)(ab + swz(wm * 32 + mi * 16 + colf, kb));
#pragma unroll
            for (int ni = 0; ni < 4; ++ni)
                bf[ni] = *(const s16x8*)(bb_ + swz(wn * 64 + ni * 16 + colf, kb));
#pragma unroll
            for (int mi = 0; mi < 2; ++mi)
#pragma unroll
                for (int ni = 0; ni < 4; ++ni)
                    acc[mi][ni] = __builtin_amdgcn_mfma_f32_16x16x32_bf16(
                        af[mi], bf[ni], acc[mi][ni], 0, 0, 0);
        }
    };
    load_global(0);
    write_lds(0);
    __syncthreads();
    int buf = 0;
#pragma unroll 1
    for (int kt = 0; kt < 8; ++kt) {
        if (kt < 7) load_global((kt + 1) << 6);
        compute(buf);
        if (kt < 7) write_lds(buf ^ 1);
        __syncthreads();
        buf ^= 1;
    }
    float* cbuf = (float*)smem;
    const int rowg = lane >> 4;
#pragma unroll
    for (int ni = 0; ni < 4; ++ni) {
        const int c = wn * 64 + ni * 16 + colf;
#pragma unroll
        for (int mi = 0; mi < 2; ++mi) {
            const int r = wm * 32 + mi * 16 + rowg * 4;
            f32x4 v = acc[mi][ni];
            cbuf[(r + 0) * 132 + c] = v[0];
            cbuf[(r + 1) * 132 + c] = v[1];
            cbuf[(r + 2) * 132 + c] = v[2];
            cbuf[(r + 3) * 132 + c] = v[3];
        }
    }
    __syncthreads();
    const int rr = tid >> 5;
    const int cc = (tid & 31) << 2;
    const float4 bv = *(const float4*)(bias + (g << 9) + n0 + cc);
#pragma unroll
    for (int it = 0; it < 8; ++it) {
        const int row = it * 8 + rr;
        float4 v = *(const float4*)(cbuf + row * 132 + cc);
        float4 o4; o4.x = v.x + bv.x; o4.y = v.y + bv.y;
                   o4.z = v.z + bv.z; o4.w = v.w + bv.w;
        *(float4*)(out + ((size_t)(bb * TTOT) + t0 + row) * DOUT + n0 + cc) = o4;
    }
}

extern "C" void kernel_launch(void* const* d_in, const int* in_sizes, int n_in,
                              void* d_out, int out_size, void* d_ws, size_t ws_size,
                              hipStream_t stream) {
    const float* x    = (const float*)d_in[0];
    const float* W    = (const float*)d_in[1];
    const float* bias = (const float*)d_in[2];
    float* out = (float*)d_out;

    const size_t wbytes = (size_t)NG * DOUT * DIN * sizeof(ushort);  // 4 MB

    if (ws_size >= wbytes) {
        ushort* wbf = (ushort*)d_ws;
        wconv_kernel<<<1024, 256, 0, stream>>>(W, wbf);
        gemm_kernel<<<BATCH * NJOB * 4, 512, 0, stream>>>(x, wbf, bias, out);
    } else {
        gemm_fallback<<<BATCH * 64 * 4, 256, 0, stream>>>(x, W, bias, out);
    }
}